// Round 8
// baseline (450.259 us; speedup 1.0000x reference)
//
#include <hip/hip_runtime.h>
#include <stdint.h>

#define N_NODES 100000
#define N_EDGES 500000
#define D 128
#define NTILES 6250    // N_NODES / 16
#define NPART 8        // one partition per XCD
#define PART_SZ 12500  // N_NODES / NPART (exact)
#define CHUNKS 125     // edge-list chunks per partition group
#define CH_EDGES 4000  // N_EDGES / CHUNKS (exact)
#define SBLK 49        // scan blocks: ceil(100000 / 2048)
#define PREP_BLKS 32   // prep_w blocks inside fused kernel 1
#define CNT_BLKS 2048  // count blocks inside fused kernel 1
// counters: 16B stride per node, 4 edge-keyed replica slots (k = e & 3)

typedef __bf16 bf16x8 __attribute__((ext_vector_type(8)));
typedef float f32x4 __attribute__((ext_vector_type(4)));

__device__ __forceinline__ unsigned short f2bf(float f) {
    union { float f; unsigned u; } v; v.f = f;
    unsigned u = v.u;
    u += 0x7fffu + ((u >> 16) & 1u);   // round-to-nearest-even
    return (unsigned short)(u >> 16);
}

__device__ __forceinline__ float asf(unsigned u) {
    union { unsigned u; float f; } x; x.u = u; return x.f;
}

// ---------------------------------------------------------------------------
// Fused kernel 1: blocks [0,32) shuffle weights into MFMA B-fragment order;
// blocks [32, 32+2048) count degrees into 4 edge-keyed replica slots per node
// (k = flat_e & 3; 500000 % 4 == 0 so flat and per-relation indices agree).
__global__ __launch_bounds__(256) void prep_count_k(const float* __restrict__ W0,
                                                    const float* __restrict__ W,
                                                    unsigned short* __restrict__ fw,
                                                    const int* __restrict__ ea,
                                                    const int* __restrict__ eb,
                                                    int* __restrict__ counts_p) {
    const int bid = blockIdx.x;
    if (bid < PREP_BLKS) {
        const int gid = bid * 256 + threadIdx.x;          // 0..8191
        const int l = gid & 63;
        const int s = (gid >> 6) & 3;
        const int n = (gid >> 8) & 7;
        const int m = gid >> 11;                          // 0..3
        const float* src = (m == 0) ? W0 : (W + (m - 1) * D * D);
        const int colw = n * 16 + (l & 15);
        const int k0 = s * 32 + ((l >> 4) << 3);
        unsigned short v[8];
#pragma unroll
        for (int j = 0; j < 8; ++j) v[j] = f2bf(src[(k0 + j) * D + colw]);
        uint4 o;
        o.x = v[0] | ((unsigned)v[1] << 16);
        o.y = v[2] | ((unsigned)v[3] << 16);
        o.z = v[4] | ((unsigned)v[5] << 16);
        o.w = v[6] | ((unsigned)v[7] << 16);
        reinterpret_cast<uint4*>(fw)[gid] = o;
    } else {
        const int stride = CNT_BLKS * 256;
        for (int e = (bid - PREP_BLKS) * 256 + threadIdx.x; e < 3 * N_EDGES; e += stride) {
            const int k = e & 3;
            atomicAdd(&counts_p[(ea[e] << 2) | k], 1);
            atomicAdd(&counts_p[(eb[e] << 2) | k], 1);
        }
    }
}

// ---------------------------------------------------------------------------
// Phase 1: per-block exclusive scan over node degrees (sum of 4 replica
// slots), writing offs; ALSO rewrites each node's 4 slots with INCLUSIVE
// prefixes (c0, c0+c1, c0+c1+c2, deg) -- the countdown initializers that give
// each replica a disjoint slot range in fill_k.
__global__ __launch_bounds__(256) void scan1_k(int* __restrict__ counts_p,
                                               int* __restrict__ offs,
                                               int* __restrict__ bsum) {
    __shared__ int sums[256];
    const int t = threadIdx.x;
    const int base = blockIdx.x * 2048 + t * 8;
    uint4* cp = reinterpret_cast<uint4*>(counts_p);
    int v[8];
    int s = 0;
#pragma unroll
    for (int j = 0; j < 8; ++j) {
        const int idx = base + j;
        if (idx < N_NODES) {
            uint4 c = cp[idx];
            uint4 w;
            w.x = c.x;
            w.y = w.x + c.y;
            w.z = w.y + c.z;
            w.w = w.z + c.w;
            cp[idx] = w;
            v[j] = (int)w.w;
        } else {
            v[j] = 0;
        }
        s += v[j];
    }
    sums[t] = s;
    __syncthreads();
    for (int off = 1; off < 256; off <<= 1) {
        const int tv = (t >= off) ? sums[t - off] : 0;
        __syncthreads();
        sums[t] += tv;
        __syncthreads();
    }
    int excl = sums[t] - s;
#pragma unroll
    for (int j = 0; j < 8; ++j) {
        const int idx = base + j;
        if (idx < N_NODES) offs[idx] = excl;
        excl += v[j];
    }
    if (t == 255) bsum[blockIdx.x] = sums[255];
}

// Phase 2: scan the 49 block totals (single 64-thread block).
__global__ __launch_bounds__(64) void scan2_k(const int* __restrict__ bsum,
                                              int* __restrict__ bpre,
                                              int* __restrict__ offs) {
    __shared__ int s[64];
    const int t = threadIdx.x;
    const int v = (t < SBLK) ? bsum[t] : 0;
    s[t] = v;
    __syncthreads();
    for (int off = 1; off < 64; off <<= 1) {
        const int tv = (t >= off) ? s[t - off] : 0;
        __syncthreads();
        s[t] += tv;
        __syncthreads();
    }
    bpre[t] = s[t] - v;                    // exclusive block prefix
    if (t == 63) offs[N_NODES] = s[63];    // grand total (= 3,000,000)
}

// Phase 3: add block prefixes back.
__global__ __launch_bounds__(256) void scan3_k(int* __restrict__ offs,
                                               const int* __restrict__ bpre) {
    const int add = bpre[blockIdx.x];
    const int base = blockIdx.x * 2048 + threadIdx.x * 8;
#pragma unroll
    for (int j = 0; j < 8; ++j) {
        const int idx = base + j;
        if (idx < N_NODES) offs[idx] += add;
    }
}

// ---------------------------------------------------------------------------
// XCD-partitioned CSR fill, 3000 blocks (~70% occupancy) to hide the
// atomic round-trip latency. Replica slot k = e & 3 matches the count pass;
// slot value counts DOWN from its inclusive prefix, so replica k owns
// positions [offs+prefix_{k-1}, offs+prefix_k).
__global__ __launch_bounds__(256) void fill_k(const int* __restrict__ ea,
                                              const int* __restrict__ eb,
                                              const int* __restrict__ offs,
                                              int* __restrict__ counts_p,
                                              int* __restrict__ eidx) {
    const int bid = blockIdx.x;
    const int p = bid & (NPART - 1);
    const int j = bid >> 3;            // 0..374
    const int r = j / CHUNKS;          // relation 0..2
    const int chunk = j - r * CHUNKS;  // 0..124
    const int lo = p * PART_SZ;
    const int e0 = chunk * CH_EDGES;
    const int e1 = e0 + CH_EDGES;
    const int* pa = ea + (size_t)r * N_EDGES;
    const int* pb = eb + (size_t)r * N_EDGES;
    const int roff = r * N_NODES;
    for (int e = e0 + threadIdx.x; e < e1; e += 256) {
        const int a = pa[e];
        const int b = pb[e];
        const int k = e & 3;
        if ((unsigned)(a - lo) < (unsigned)PART_SZ) {
            const int base = offs[a];
            const int old = atomicSub(&counts_p[(a << 2) | k], 1);
            eidx[base + old - 1] = b + roff;
        }
        if ((unsigned)(b - lo) < (unsigned)PART_SZ) {
            const int base = offs[b];
            const int old = atomicSub(&counts_p[(b << 2) | k], 1);
            eidx[base + old - 1] = a + roff;
        }
    }
}

// ---------------------------------------------------------------------------
// 4-matrix GEMM: reads X once, writes out = X@W0 (f32) and
// Yb[r] = bf16(X@W[r]) for r=0..2 (contiguous 300000x128 bf16).
__global__ __launch_bounds__(256) void gemm4_k(const float* __restrict__ X,
                                               const unsigned short* __restrict__ fw,
                                               float* __restrict__ out,
                                               unsigned short* __restrict__ Yb) {
    const int wid = threadIdx.x >> 6;
    const int l = threadIdx.x & 63;
    const int t = blockIdx.x * 4 + wid;
    if (t >= NTILES) return;
    const float4* xr = reinterpret_cast<const float4*>(
        X + (size_t)(t * 16 + (l & 15)) * D + ((l >> 4) << 3));
    bf16x8 a[4];
#pragma unroll
    for (int s = 0; s < 4; ++s) {
        const float4 f0 = xr[s * 8];
        const float4 f1 = xr[s * 8 + 1];
        union { uint4 u; bf16x8 h; } pk;
        pk.u.x = f2bf(f0.x) | ((unsigned)f2bf(f0.y) << 16);
        pk.u.y = f2bf(f0.z) | ((unsigned)f2bf(f0.w) << 16);
        pk.u.z = f2bf(f1.x) | ((unsigned)f2bf(f1.y) << 16);
        pk.u.w = f2bf(f1.z) | ((unsigned)f2bf(f1.w) << 16);
        a[s] = pk.h;
    }
    const bf16x8* bw = reinterpret_cast<const bf16x8*>(fw) + l;
    const int rbase = t * 16 + ((l >> 4) << 2);   // C/D: col=lane&15, row=(lane>>4)*4+q
    const int colb = l & 15;
#pragma unroll
    for (int m = 0; m < 4; ++m) {
        f32x4 acc[8];
#pragma unroll
        for (int n = 0; n < 8; ++n) acc[n] = (f32x4){0.f, 0.f, 0.f, 0.f};
#pragma unroll
        for (int n = 0; n < 8; ++n) {
#pragma unroll
            for (int s = 0; s < 4; ++s)
                acc[n] = __builtin_amdgcn_mfma_f32_16x16x32_bf16(
                    a[s], bw[m * 2048 + (n * 4 + s) * 64], acc[n], 0, 0, 0);
        }
        if (m == 0) {
#pragma unroll
            for (int n = 0; n < 8; ++n)
#pragma unroll
                for (int q = 0; q < 4; ++q)
                    out[(size_t)(rbase + q) * D + n * 16 + colb] = acc[n][q];
        } else {
            unsigned short* yo = Yb + (size_t)(m - 1) * N_NODES * D;
#pragma unroll
            for (int n = 0; n < 8; ++n)
#pragma unroll
                for (int q = 0; q < 4; ++q)
                    yo[(size_t)(rbase + q) * D + n * 16 + colb] = f2bf(acc[n][q]);
        }
    }
}

// ---------------------------------------------------------------------------
// Pull gather over the combined CSR: one wave per destination node, 16x/8x/4x
// unrolled neighbor loop. out = (out + sum_{src} Yb[src]) * norms[n] + bias.
__global__ __launch_bounds__(256) void gather_k(const unsigned* __restrict__ Yu,
                                                const int* __restrict__ offs,
                                                const int* __restrict__ eidx,
                                                float* __restrict__ out,
                                                const float* __restrict__ norms,
                                                const float* __restrict__ bias) {
    const int wid = threadIdx.x >> 6;
    const int l = threadIdx.x & 63;
    const int n = blockIdx.x * 4 + wid;
    if (n >= N_NODES) return;
    const int s0 = offs[n];
    const int s1 = offs[n + 1];
    float ax = 0.f, ay = 0.f, bx = 0.f, by = 0.f;
    int i = s0;
    for (; i + 16 <= s1; i += 16) {
        int c[16];
        unsigned v[16];
#pragma unroll
        for (int j = 0; j < 16; ++j) c[j] = eidx[i + j];
#pragma unroll
        for (int j = 0; j < 16; ++j) v[j] = Yu[(size_t)c[j] * 64 + l];
#pragma unroll
        for (int j = 0; j < 16; j += 2) {
            ax += asf(v[j] << 16);     ay += asf(v[j] & 0xffff0000u);
            bx += asf(v[j + 1] << 16); by += asf(v[j + 1] & 0xffff0000u);
        }
    }
    for (; i + 8 <= s1; i += 8) {
        int c[8];
        unsigned v[8];
#pragma unroll
        for (int j = 0; j < 8; ++j) c[j] = eidx[i + j];
#pragma unroll
        for (int j = 0; j < 8; ++j) v[j] = Yu[(size_t)c[j] * 64 + l];
#pragma unroll
        for (int j = 0; j < 8; j += 2) {
            ax += asf(v[j] << 16);     ay += asf(v[j] & 0xffff0000u);
            bx += asf(v[j + 1] << 16); by += asf(v[j + 1] & 0xffff0000u);
        }
    }
    for (; i + 4 <= s1; i += 4) {
        const int c0 = eidx[i], c1 = eidx[i + 1], c2 = eidx[i + 2], c3 = eidx[i + 3];
        const unsigned v0 = Yu[(size_t)c0 * 64 + l];
        const unsigned v1 = Yu[(size_t)c1 * 64 + l];
        const unsigned v2 = Yu[(size_t)c2 * 64 + l];
        const unsigned v3 = Yu[(size_t)c3 * 64 + l];
        ax += asf(v0 << 16); ay += asf(v0 & 0xffff0000u);
        bx += asf(v1 << 16); by += asf(v1 & 0xffff0000u);
        ax += asf(v2 << 16); ay += asf(v2 & 0xffff0000u);
        bx += asf(v3 << 16); by += asf(v3 & 0xffff0000u);
    }
    for (; i < s1; ++i) {
        const unsigned v = Yu[(size_t)eidx[i] * 64 + l];
        ax += asf(v << 16); ay += asf(v & 0xffff0000u);
    }
    float* op = out + (size_t)n * D + l * 2;
    const float2 cur = *reinterpret_cast<const float2*>(op);
    const float nm = norms[n];
    const float2 bb = *reinterpret_cast<const float2*>(bias + l * 2);
    float2 res;
    res.x = (cur.x + ax + bx) * nm + bb.x;
    res.y = (cur.y + ay + by) * nm + bb.y;
    *reinterpret_cast<float2*>(op) = res;
}

// ---------------------------------------------------------------------------
extern "C" void kernel_launch(void* const* d_in, const int* in_sizes, int n_in,
                              void* d_out, int out_size, void* d_ws, size_t ws_size,
                              hipStream_t stream) {
    const float* X      = (const float*)d_in[0];
    const int*   ref_a  = (const int*)d_in[1];
    const int*   ref_b  = (const int*)d_in[2];
    const float* norms  = (const float*)d_in[3];
    const float* W0     = (const float*)d_in[4];
    const float* W      = (const float*)d_in[5];
    const float* bias   = (const float*)d_in[6];
    float* out = (float*)d_out;

    char* ws = (char*)d_ws;
    unsigned short* Yb   = (unsigned short*)ws;              // 76,800,000 B
    int* eidx            = (int*)(ws + 76800000);            // 12,000,000 B
    unsigned short* fw   = (unsigned short*)(ws + 88800000); //    131,072 B
    int* offs            = (int*)(ws + 88931072);            //    400,016 B
    int* bsum            = (int*)(ws + 89331088);            //        256 B
    int* bpre            = (int*)(ws + 89331344);            //        272 B
    int* counts_p        = (int*)(ws + 89331616);            //  1,600,000 B
    // total 90,931,616 B <= proven 92,531,104 B

    // zero the padded replica counters
    hipMemsetAsync(ws + 89331616, 0, 1600000, stream);

    // weights prep || single-pass degree count (4 replica slots per node)
    prep_count_k<<<PREP_BLKS + CNT_BLKS, 256, 0, stream>>>(W0, W, fw, ref_a, ref_b, counts_p);

    // 3-phase parallel exclusive scan -> offs; counts_p -> inclusive prefixes
    scan1_k<<<SBLK, 256, 0, stream>>>(counts_p, offs, bsum);
    scan2_k<<<1, 64, 0, stream>>>(bsum, bpre, offs);
    scan3_k<<<SBLK, 256, 0, stream>>>(offs, bpre);

    // XCD-partitioned CSR fill; replica countdown allocator
    fill_k<<<CHUNKS * NPART * 3, 256, 0, stream>>>(ref_a, ref_b, offs, counts_p, eidx);

    // 4-matrix GEMM
    gemm4_k<<<(NTILES + 3) / 4, 256, 0, stream>>>(X, fw, out, Yb);

    // single gather over combined CSR + fused finalize
    gather_k<<<(N_NODES + 3) / 4, 256, 0, stream>>>(
        (const unsigned*)Yb, offs, eidx, out, norms, bias);
}

// Round 9
// 427.357 us; speedup vs baseline: 1.0536x; 1.0536x over previous
//
#include <hip/hip_runtime.h>
#include <stdint.h>

#define N_NODES 100000
#define N_EDGES 500000
#define D 128
#define NTILES 6250    // N_NODES / 16
#define NPART 8        // one partition per XCD
#define PART_SZ 12500  // N_NODES / NPART (exact)
#define CHUNKS 125     // edge-list chunks per partition group
#define CH_EDGES 4000  // N_EDGES / CHUNKS (exact)
#define SBLK 49        // scan blocks: ceil(100000 / 2048)
#define PREP_BLKS 32   // prep_w blocks inside fused kernel 1
#define CNT_BLKS 2048  // count blocks inside fused kernel 1
#define FILL_BLKS 3000 // CHUNKS * NPART * 3
#define GEMM_BLKS 1568 // ceil(6250/4)=1563 padded to a multiple of 8
// counters: 16B stride per node, 4 edge-keyed replica slots (k = e & 3)

typedef __bf16 bf16x8 __attribute__((ext_vector_type(8)));
typedef float f32x4 __attribute__((ext_vector_type(4)));

__device__ __forceinline__ unsigned short f2bf(float f) {
    union { float f; unsigned u; } v; v.f = f;
    unsigned u = v.u;
    u += 0x7fffu + ((u >> 16) & 1u);   // round-to-nearest-even
    return (unsigned short)(u >> 16);
}

__device__ __forceinline__ float asf(unsigned u) {
    union { unsigned u; float f; } x; x.u = u; return x.f;
}

// ---------------------------------------------------------------------------
// Fused kernel 1: blocks [0,32) shuffle weights into MFMA B-fragment order;
// blocks [32, 32+2048) count degrees into 4 edge-keyed replica slots per node.
__global__ __launch_bounds__(256) void prep_count_k(const float* __restrict__ W0,
                                                    const float* __restrict__ W,
                                                    unsigned short* __restrict__ fw,
                                                    const int* __restrict__ ea,
                                                    const int* __restrict__ eb,
                                                    int* __restrict__ counts_p) {
    const int bid = blockIdx.x;
    if (bid < PREP_BLKS) {
        const int gid = bid * 256 + threadIdx.x;          // 0..8191
        const int l = gid & 63;
        const int s = (gid >> 6) & 3;
        const int n = (gid >> 8) & 7;
        const int m = gid >> 11;                          // 0..3
        const float* src = (m == 0) ? W0 : (W + (m - 1) * D * D);
        const int colw = n * 16 + (l & 15);
        const int k0 = s * 32 + ((l >> 4) << 3);
        unsigned short v[8];
#pragma unroll
        for (int j = 0; j < 8; ++j) v[j] = f2bf(src[(k0 + j) * D + colw]);
        uint4 o;
        o.x = v[0] | ((unsigned)v[1] << 16);
        o.y = v[2] | ((unsigned)v[3] << 16);
        o.z = v[4] | ((unsigned)v[5] << 16);
        o.w = v[6] | ((unsigned)v[7] << 16);
        reinterpret_cast<uint4*>(fw)[gid] = o;
    } else {
        const int stride = CNT_BLKS * 256;
        for (int e = (bid - PREP_BLKS) * 256 + threadIdx.x; e < 3 * N_EDGES; e += stride) {
            const int k = e & 3;
            atomicAdd(&counts_p[(ea[e] << 2) | k], 1);
            atomicAdd(&counts_p[(eb[e] << 2) | k], 1);
        }
    }
}

// ---------------------------------------------------------------------------
// Phase 1: per-block exclusive scan over node degrees (sum of 4 replica
// slots), writing offs; rewrites each node's slots with INCLUSIVE prefixes
// (countdown initializers giving each replica a disjoint slot range).
__global__ __launch_bounds__(256) void scan1_k(int* __restrict__ counts_p,
                                               int* __restrict__ offs,
                                               int* __restrict__ bsum) {
    __shared__ int sums[256];
    const int t = threadIdx.x;
    const int base = blockIdx.x * 2048 + t * 8;
    uint4* cp = reinterpret_cast<uint4*>(counts_p);
    int v[8];
    int s = 0;
#pragma unroll
    for (int j = 0; j < 8; ++j) {
        const int idx = base + j;
        if (idx < N_NODES) {
            uint4 c = cp[idx];
            uint4 w;
            w.x = c.x;
            w.y = w.x + c.y;
            w.z = w.y + c.z;
            w.w = w.z + c.w;
            cp[idx] = w;
            v[j] = (int)w.w;
        } else {
            v[j] = 0;
        }
        s += v[j];
    }
    sums[t] = s;
    __syncthreads();
    for (int off = 1; off < 256; off <<= 1) {
        const int tv = (t >= off) ? sums[t - off] : 0;
        __syncthreads();
        sums[t] += tv;
        __syncthreads();
    }
    int excl = sums[t] - s;
#pragma unroll
    for (int j = 0; j < 8; ++j) {
        const int idx = base + j;
        if (idx < N_NODES) offs[idx] = excl;
        excl += v[j];
    }
    if (t == 255) bsum[blockIdx.x] = sums[255];
}

// Phase 2: scan the 49 block totals (single 64-thread block).
__global__ __launch_bounds__(64) void scan2_k(const int* __restrict__ bsum,
                                              int* __restrict__ bpre,
                                              int* __restrict__ offs) {
    __shared__ int s[64];
    const int t = threadIdx.x;
    const int v = (t < SBLK) ? bsum[t] : 0;
    s[t] = v;
    __syncthreads();
    for (int off = 1; off < 64; off <<= 1) {
        const int tv = (t >= off) ? s[t - off] : 0;
        __syncthreads();
        s[t] += tv;
        __syncthreads();
    }
    bpre[t] = s[t] - v;                    // exclusive block prefix
    if (t == 63) offs[N_NODES] = s[63];    // grand total (= 3,000,000)
}

// Phase 3: add block prefixes back.
__global__ __launch_bounds__(256) void scan3_k(int* __restrict__ offs,
                                               const int* __restrict__ bpre) {
    const int add = bpre[blockIdx.x];
    const int base = blockIdx.x * 2048 + threadIdx.x * 8;
#pragma unroll
    for (int j = 0; j < 8; ++j) {
        const int idx = base + j;
        if (idx < N_NODES) offs[idx] += add;
    }
}

// ---------------------------------------------------------------------------
// Fused kernel 2: blocks [0, FILL_BLKS) = XCD-partitioned CSR fill (replica
// countdown allocator, R8 config); blocks [FILL_BLKS, +GEMM_BLKS) = 4-matrix
// GEMM. Fill is latency-bound (low VALU, low BW) and GEMM is MFMA/BW-bound;
// they overlap on the CUs instead of serializing. Fill placed FIRST (long pole).
__global__ __launch_bounds__(256) void fill_gemm_k(const int* __restrict__ ea,
                                                   const int* __restrict__ eb,
                                                   const int* __restrict__ offs,
                                                   int* __restrict__ counts_p,
                                                   int* __restrict__ eidx,
                                                   const float* __restrict__ X,
                                                   const unsigned short* __restrict__ fw,
                                                   float* __restrict__ out,
                                                   unsigned short* __restrict__ Yb) {
    const int bid = blockIdx.x;
    if (bid < FILL_BLKS) {
        const int p = bid & (NPART - 1);
        const int j = bid >> 3;            // 0..374
        const int r = j / CHUNKS;          // relation 0..2
        const int chunk = j - r * CHUNKS;  // 0..124
        const int lo = p * PART_SZ;
        const int e0 = chunk * CH_EDGES;
        const int e1 = e0 + CH_EDGES;
        const int* pa = ea + (size_t)r * N_EDGES;
        const int* pb = eb + (size_t)r * N_EDGES;
        const int roff = r * N_NODES;
        for (int e = e0 + threadIdx.x; e < e1; e += 256) {
            const int a = pa[e];
            const int b = pb[e];
            const int k = e & 3;
            if ((unsigned)(a - lo) < (unsigned)PART_SZ) {
                const int base = offs[a];
                const int old = atomicSub(&counts_p[(a << 2) | k], 1);
                eidx[base + old - 1] = b + roff;
            }
            if ((unsigned)(b - lo) < (unsigned)PART_SZ) {
                const int base = offs[b];
                const int old = atomicSub(&counts_p[(b << 2) | k], 1);
                eidx[base + old - 1] = a + roff;
            }
        }
    } else {
        const int wid = threadIdx.x >> 6;
        const int l = threadIdx.x & 63;
        const int t = (bid - FILL_BLKS) * 4 + wid;
        if (t >= NTILES) return;
        const float4* xr = reinterpret_cast<const float4*>(
            X + (size_t)(t * 16 + (l & 15)) * D + ((l >> 4) << 3));
        bf16x8 a[4];
#pragma unroll
        for (int s = 0; s < 4; ++s) {
            const float4 f0 = xr[s * 8];
            const float4 f1 = xr[s * 8 + 1];
            union { uint4 u; bf16x8 h; } pk;
            pk.u.x = f2bf(f0.x) | ((unsigned)f2bf(f0.y) << 16);
            pk.u.y = f2bf(f0.z) | ((unsigned)f2bf(f0.w) << 16);
            pk.u.z = f2bf(f1.x) | ((unsigned)f2bf(f1.y) << 16);
            pk.u.w = f2bf(f1.z) | ((unsigned)f2bf(f1.w) << 16);
            a[s] = pk.h;
        }
        const bf16x8* bw = reinterpret_cast<const bf16x8*>(fw) + l;
        const int rbase = t * 16 + ((l >> 4) << 2);   // C/D: col=lane&15, row=(lane>>4)*4+q
        const int colb = l & 15;
#pragma unroll
        for (int m = 0; m < 4; ++m) {
            f32x4 acc[8];
#pragma unroll
            for (int n = 0; n < 8; ++n) acc[n] = (f32x4){0.f, 0.f, 0.f, 0.f};
#pragma unroll
            for (int n = 0; n < 8; ++n) {
#pragma unroll
                for (int s = 0; s < 4; ++s)
                    acc[n] = __builtin_amdgcn_mfma_f32_16x16x32_bf16(
                        a[s], bw[m * 2048 + (n * 4 + s) * 64], acc[n], 0, 0, 0);
            }
            if (m == 0) {
#pragma unroll
                for (int n = 0; n < 8; ++n)
#pragma unroll
                    for (int q = 0; q < 4; ++q)
                        out[(size_t)(rbase + q) * D + n * 16 + colb] = acc[n][q];
            } else {
                unsigned short* yo = Yb + (size_t)(m - 1) * N_NODES * D;
#pragma unroll
                for (int n = 0; n < 8; ++n)
#pragma unroll
                    for (int q = 0; q < 4; ++q)
                        yo[(size_t)(rbase + q) * D + n * 16 + colb] = f2bf(acc[n][q]);
            }
        }
    }
}

// ---------------------------------------------------------------------------
// Paired-row pull gather: lanes 0-31 process even rows, lanes 32-63 odd rows,
// uint2 (8B) per lane -> TWO 256B rows per VMEM instruction (halves the
// per-wave VMEM instruction count vs one-row-per-instruction).
// Final cross-half combine via shfl_xor(32); lanes<32 write float4.
__global__ __launch_bounds__(256) void gather_k(const unsigned* __restrict__ Yu,
                                                const int* __restrict__ offs,
                                                const int* __restrict__ eidx,
                                                float* __restrict__ out,
                                                const float* __restrict__ norms,
                                                const float* __restrict__ bias) {
    const int wid = threadIdx.x >> 6;
    const int l = threadIdx.x & 63;
    const int n = blockIdx.x * 4 + wid;
    if (n >= N_NODES) return;
    const int rs = l >> 5;              // which row of the pair
    const int sub = l & 31;             // uint2 index within row
    const uint2* Y2 = reinterpret_cast<const uint2*>(Yu);   // row = 32 uint2
    const int s0 = offs[n];
    const int s1 = offs[n + 1];
    float a0 = 0.f, a1 = 0.f, a2 = 0.f, a3 = 0.f;
    int i = s0;
    for (; i + 16 <= s1; i += 16) {     // 8 pairs = 16 rows, 8 loads in flight
        int c[8];
        uint2 v[8];
#pragma unroll
        for (int k = 0; k < 8; ++k) c[k] = eidx[i + 2 * k + rs];
#pragma unroll
        for (int k = 0; k < 8; ++k) v[k] = Y2[(size_t)c[k] * 32 + sub];
#pragma unroll
        for (int k = 0; k < 8; ++k) {
            a0 += asf(v[k].x << 16); a1 += asf(v[k].x & 0xffff0000u);
            a2 += asf(v[k].y << 16); a3 += asf(v[k].y & 0xffff0000u);
        }
    }
    for (; i + 4 <= s1; i += 4) {       // 2 pairs
        const int c0 = eidx[i + rs];
        const int c1 = eidx[i + 2 + rs];
        const uint2 v0 = Y2[(size_t)c0 * 32 + sub];
        const uint2 v1 = Y2[(size_t)c1 * 32 + sub];
        a0 += asf(v0.x << 16); a1 += asf(v0.x & 0xffff0000u);
        a2 += asf(v0.y << 16); a3 += asf(v0.y & 0xffff0000u);
        a0 += asf(v1.x << 16); a1 += asf(v1.x & 0xffff0000u);
        a2 += asf(v1.y << 16); a3 += asf(v1.y & 0xffff0000u);
    }
    for (; i < s1; i += 2) {            // tail pair (odd-degree: hi half idles)
        const int j = i + rs;
        if (j < s1) {
            const int c = eidx[j];
            const uint2 v = Y2[(size_t)c * 32 + sub];
            a0 += asf(v.x << 16); a1 += asf(v.x & 0xffff0000u);
            a2 += asf(v.y << 16); a3 += asf(v.y & 0xffff0000u);
        }
    }
    a0 += __shfl_xor(a0, 32);
    a1 += __shfl_xor(a1, 32);
    a2 += __shfl_xor(a2, 32);
    a3 += __shfl_xor(a3, 32);
    if (rs == 0) {
        float4* op = reinterpret_cast<float4*>(out + (size_t)n * D) + sub;
        const float4 cur = *op;
        const float nm = norms[n];
        const float4 bb = reinterpret_cast<const float4*>(bias)[sub];
        float4 res;
        res.x = (cur.x + a0) * nm + bb.x;
        res.y = (cur.y + a1) * nm + bb.y;
        res.z = (cur.z + a2) * nm + bb.z;
        res.w = (cur.w + a3) * nm + bb.w;
        *op = res;
    }
}

// ---------------------------------------------------------------------------
extern "C" void kernel_launch(void* const* d_in, const int* in_sizes, int n_in,
                              void* d_out, int out_size, void* d_ws, size_t ws_size,
                              hipStream_t stream) {
    const float* X      = (const float*)d_in[0];
    const int*   ref_a  = (const int*)d_in[1];
    const int*   ref_b  = (const int*)d_in[2];
    const float* norms  = (const float*)d_in[3];
    const float* W0     = (const float*)d_in[4];
    const float* W      = (const float*)d_in[5];
    const float* bias   = (const float*)d_in[6];
    float* out = (float*)d_out;

    char* ws = (char*)d_ws;
    unsigned short* Yb   = (unsigned short*)ws;              // 76,800,000 B
    int* eidx            = (int*)(ws + 76800000);            // 12,000,000 B
    unsigned short* fw   = (unsigned short*)(ws + 88800000); //    131,072 B
    int* offs            = (int*)(ws + 88931072);            //    400,016 B
    int* bsum            = (int*)(ws + 89331088);            //        256 B
    int* bpre            = (int*)(ws + 89331344);            //        272 B
    int* counts_p        = (int*)(ws + 89331616);            //  1,600,000 B
    // total 90,931,616 B <= proven 92,531,104 B

    // zero the padded replica counters
    hipMemsetAsync(ws + 89331616, 0, 1600000, stream);

    // weights prep || single-pass degree count (4 replica slots per node)
    prep_count_k<<<PREP_BLKS + CNT_BLKS, 256, 0, stream>>>(W0, W, fw, ref_a, ref_b, counts_p);

    // 3-phase parallel exclusive scan -> offs; counts_p -> inclusive prefixes
    scan1_k<<<SBLK, 256, 0, stream>>>(counts_p, offs, bsum);
    scan2_k<<<1, 64, 0, stream>>>(bsum, bpre, offs);
    scan3_k<<<SBLK, 256, 0, stream>>>(offs, bpre);

    // CSR fill || 4-matrix GEMM (role-split grid, fill first)
    fill_gemm_k<<<FILL_BLKS + GEMM_BLKS, 256, 0, stream>>>(
        ref_a, ref_b, offs, counts_p, eidx, X, fw, out, Yb);

    // paired-row gather over combined CSR + fused finalize
    gather_k<<<(N_NODES + 3) / 4, 256, 0, stream>>>(
        (const unsigned*)Yb, offs, eidx, out, norms, bias);
}